// Round 5
// baseline (183.030 us; speedup 1.0000x reference)
//
#include <hip/hip_runtime.h>

#define NPG 100     // nodes per graph
#define HF 64       // hidden width
#define NROW 128    // node rows padded to 4 x 32 tiles
#define SA 120      // Arm row stride (bf16): 112 k-slots + 8 pad
#define ST 72       // Trm row stride (bf16): 64 + 8 pad
#define SAT 136     // Tt row stride (bf16): 128 + 8 pad

typedef float  f4   __attribute__((ext_vector_type(4)));
typedef float  f16v __attribute__((ext_vector_type(16)));
typedef short  bf8  __attribute__((ext_vector_type(8)));

#define SZ_ARM (NROW * SA * 2)        // 30720
#define SZ_TRM (NROW * ST * 2)        // 18432
#define SZ_TT  (HF * SAT * 2)         // 17408
#define OFF_ARM 0
#define OFF_TRM SZ_ARM                // 30720
#define OFF_TT  (OFF_TRM + SZ_TRM)    // 49152 (ends 66560)
#define OFF_AF  OFF_TRM               // fp32 A staging 40000 B overlay (ends 70720)
#define OFF_MISC 70720                // (overlay region padded to 40000)
#define SMEM_BYTES (OFF_MISC + 1792)  // 72512 -> 2 blocks/CU

// bf16 weight workspace (d_ws), layout Wt[k5][fo][fi]:
//   W1t [5][64][16] @ 0  (fi zero-padded 3->16)
//   W2t [5][64][64] @ 5120
//   W3t [5][64][64] @ 25600
#define WT_TOTAL 46080

__device__ __forceinline__ unsigned short f2bf(float f) {
    unsigned u = __float_as_uint(f);
    u += 0x7fffu + ((u >> 16) & 1u);   // round-to-nearest-even
    return (unsigned short)(u >> 16);
}
__device__ __forceinline__ float bf2f(unsigned short h) {
    return __uint_as_float(((unsigned)h) << 16);
}
__device__ __forceinline__ f16v zerov16() {
    f16v z;
    #pragma unroll
    for (int i = 0; i < 16; i++) z[i] = 0.f;
    return z;
}

__global__ void wconv(const float* __restrict__ W1, const float* __restrict__ W2,
                      const float* __restrict__ W3, unsigned short* __restrict__ ws)
{
    int idx = blockIdx.x * 256 + threadIdx.x;
    if (idx >= WT_TOTAL) return;
    float v;
    if (idx < 5120) {
        int k5 = idx >> 10, rem = idx & 1023, fo = rem >> 4, fi = rem & 15;
        v = (fi < 3) ? W1[(k5 * 3 + fi) * HF + fo] : 0.f;
    } else if (idx < 25600) {
        int j = idx - 5120;
        int k5 = j >> 12, rem = j & 4095, fo = rem >> 6, fi = rem & 63;
        v = W2[(k5 * HF + fi) * HF + fo];
    } else {
        int j = idx - 25600;
        int k5 = j >> 12, rem = j & 4095, fo = rem >> 6, fi = rem & 63;
        v = W3[(k5 * HF + fi) * HF + fo];
    }
    ws[idx] = f2bf(v);
}

// One block per graph, 256 threads = 4 waves, 2 blocks/CU.
// LHAT (transposed): C[f][n'] = sum_n Tt[f][n] * Arm[n'][n]
//   A-op = Tt rows b128, B-op = Arm rows b128 (stored-BT trick). Single-buffer
//   Tt/Trm: A-frags to regs first, barrier, write in place. Cheb prev/old in
//   packed-bf16 registers.
// TW: O[n'][fo] += sum_fi Trm[n'][fi] * Wt[fo][fi]  (A=Trm b128, B=Wt b128)
// C/D layout: col = lane&31 (N), row = (r&3)+8*(r>>2)+4*(lane>>5) (M)
__launch_bounds__(256, 2)
__global__ void cheb32t(const float* __restrict__ x, const int* __restrict__ ei,
                        const float* __restrict__ lambda_max,
                        const unsigned short* __restrict__ Wt,
                        const float* __restrict__ b1, const float* __restrict__ b2,
                        const float* __restrict__ b3,
                        const float* __restrict__ bng, const float* __restrict__ bnb,
                        const float* __restrict__ bnm, const float* __restrict__ bnv,
                        const float* __restrict__ fc1w, const float* __restrict__ fc1b,
                        const float* __restrict__ fc2w, const float* __restrict__ fc2b,
                        float* __restrict__ out, int E_total, int epg)
{
    extern __shared__ char sm[];
    const int tid = threadIdx.x;
    const int g = blockIdx.x;
    const int ebase = g * epg, nbase = g * NPG;
    const int wg = tid >> 6, lane = tid & 63;
    const int l31 = lane & 31, hh = lane >> 5;
    const int ht  = wg & 1;          // f-tile (LHAT) / fo-tile (TW)
    const int Mt0 = (wg >> 1) * 2;   // n'-tile pair base
    const int fo  = ht * 32 + l31;   // TW output column

    float* Af     = (float*)(sm + OFF_AF);
    int*   deg    = (int*)(sm + OFF_MISC);
    float* dis    = (float*)(sm + OFF_MISC + 512);
    float* pool   = (float*)(sm + OFF_MISC + 1024);
    float* gvn    = (float*)(sm + OFF_MISC + 1280);
    float* zf     = (float*)(sm + OFF_MISC + 1536);
    float* logits = (float*)(sm + OFF_MISC + 1664);
    float* lsep   = (float*)(sm + OFF_MISC + 1728);

    const float lam = lambda_max[g];
    const float two_l = 2.0f / lam;
    const float cl = two_l - 1.0f;

    // ---------------- build dense Lhat (fp32 staging -> bf16 Arm) ----------------
    for (int i = tid; i < 2500; i += 256) ((f4*)Af)[i] = (f4){0.f, 0.f, 0.f, 0.f};
    if (tid < NPG) deg[tid] = 0;
    if (tid < HF) pool[tid] = 0.f;
    __syncthreads();
    for (int e = tid; e < epg; e += 256)
        atomicAdd(&deg[ei[ebase + e] - nbase], 1);
    __syncthreads();
    if (tid < NPG) dis[tid] = deg[tid] > 0 ? rsqrtf((float)deg[tid]) : 0.f;
    __syncthreads();
    for (int e = tid; e < epg; e += 256) {
        int r = ei[ebase + e] - nbase;
        int c = ei[E_total + ebase + e] - nbase;
        atomicAdd(&Af[r * NPG + c], -two_l * dis[r] * dis[c]);
    }
    __syncthreads();
    if (tid < NPG) Af[tid * NPG + tid] += cl;
    __syncthreads();
    for (int u = tid; u < NROW * 56; u += 256) {
        int n = u / 56, p = (u % 56) * 2;
        float v0 = (n < NPG && p     < NPG) ? Af[n * NPG + p]     : 0.f;
        float v1 = (n < NPG && p + 1 < NPG) ? Af[n * NPG + p + 1] : 0.f;
        *(unsigned*)(sm + OFF_ARM + (n * SA + p) * 2) =
            (unsigned)f2bf(v0) | ((unsigned)f2bf(v1) << 16);
    }
    __syncthreads();   // Af reads done before Trm/Tt (overlay) are overwritten

    // ---------------- init Trm + Tt: zero + x ----------------
    for (int i = tid; i < (SZ_TRM + SZ_TT) / 16; i += 256)
        ((f4*)(sm + OFF_TRM))[i] = (f4){0.f, 0.f, 0.f, 0.f};
    __syncthreads();
    if (tid < NPG) {
        unsigned short h0 = f2bf(x[(nbase + tid) * 3 + 0]);
        unsigned short h1 = f2bf(x[(nbase + tid) * 3 + 1]);
        unsigned short h2 = f2bf(x[(nbase + tid) * 3 + 2]);
        *(unsigned*)(sm + OFF_TRM + (tid * ST) * 2) = (unsigned)h0 | ((unsigned)h1 << 16);
        *(unsigned short*)(sm + OFF_TRM + (tid * ST + 2) * 2) = h2;
        *(unsigned short*)(sm + OFF_TT + (0 * SAT + tid) * 2) = h0;
        *(unsigned short*)(sm + OFF_TT + (1 * SAT + tid) * 2) = h1;
        *(unsigned short*)(sm + OFF_TT + (2 * SAT + tid) * 2) = h2;
    }
    __syncthreads();

    // ---------------- 3 ChebConv layers ----------------
    f16v acc[2];
    unsigned prev[2][8], oldr[2][8];   // packed-bf16 T_{s-1}, T_{s-2} at LHAT lane positions
    const float* bsv[3] = {b1, b2, b3};

    for (int L = 0; L < 3; L++) {
        const bool l1 = (L == 0);
        const unsigned short* Wl = l1 ? Wt : (Wt + (L == 1 ? 5120 : 25600));
        acc[0] = zerov16();
        acc[1] = zerov16();

        // prev = T0 at LHAT positions (read packed from Trm rows)
        #pragma unroll
        for (int m = 0; m < 2; m++) {
            int np = (Mt0 + m) * 32 + l31;
            #pragma unroll
            for (int q4 = 0; q4 < 4; q4++) {
                int fb = 8 * q4 + 4 * hh + 32 * ht;
                uint2 u = *(const uint2*)(sm + OFF_TRM + (np * ST + fb) * 2);
                prev[m][2 * q4] = u.x;
                prev[m][2 * q4 + 1] = u.y;
            }
        }

        auto TW = [&](int k5) {
            const int nKs = l1 ? 1 : 4;
            for (int Ks = 0; Ks < nKs; Ks++) {
                bf8 bw;
                if (l1) bw = *(const bf8*)(Wl + (k5 * 64 + fo) * 16 + 8 * hh);
                else    bw = *(const bf8*)(Wl + (k5 * 64 + fo) * 64 + Ks * 16 + 8 * hh);
                #pragma unroll
                for (int m = 0; m < 2; m++) {
                    bf8 a = *(const bf8*)(sm + OFF_TRM +
                              (((Mt0 + m) * 32 + l31) * ST + Ks * 16 + 8 * hh) * 2);
                    acc[m] = __builtin_amdgcn_mfma_f32_32x32x16_bf16(a, bw, acc[m], 0, 0, 0);
                }
            }
        };

        TW(0);
        for (int s = 1; s <= 4; s++) {
            // A-frags: Tt rows (b128), shared across both n'-tiles
            bf8 af[7];
            #pragma unroll
            for (int Ks = 0; Ks < 7; Ks++)
                af[Ks] = *(const bf8*)(sm + OFF_TT +
                           ((32 * ht + l31) * SAT + Ks * 16 + 8 * hh) * 2);
            __syncthreads();   // all Tt/Trm reads (af, TW(s-1), prev-init) done
            #pragma unroll
            for (int m = 0; m < 2; m++) {
                int np = (Mt0 + m) * 32 + l31;
                f16v c = zerov16();
                #pragma unroll
                for (int Ks = 0; Ks < 7; Ks++) {
                    bf8 b = *(const bf8*)(sm + OFF_ARM + (np * SA + Ks * 16 + 8 * hh) * 2);
                    c = __builtin_amdgcn_mfma_f32_32x32x16_bf16(af[Ks], b, c, 0, 0, 0);
                }
                unsigned short h[16];
                #pragma unroll
                for (int r = 0; r < 16; r++) {
                    float v = c[r];
                    if (s >= 2) {
                        unsigned short o = (unsigned short)
                            ((oldr[m][r >> 1] >> (16 * (r & 1))) & 0xffff);
                        v = 2.f * v - bf2f(o);
                    }
                    h[r] = f2bf(v);
                }
                #pragma unroll
                for (int p = 0; p < 8; p++) {
                    oldr[m][p] = prev[m][p];
                    prev[m][p] = (unsigned)h[2 * p] | ((unsigned)h[2 * p + 1] << 16);
                }
                // Tt writes: f strided, col np (b16 x16)
                #pragma unroll
                for (int r = 0; r < 16; r++) {
                    int f = (r & 3) + 8 * (r >> 2) + 4 * hh + 32 * ht;
                    *(unsigned short*)(sm + OFF_TT + (f * SAT + np) * 2) = h[r];
                }
                // Trm writes: row np, 4 consecutive f per reg-quad (uint2 x4)
                #pragma unroll
                for (int q4 = 0; q4 < 4; q4++) {
                    int fb = 8 * q4 + 4 * hh + 32 * ht;
                    uint2 pk;
                    pk.x = prev[m][2 * q4];
                    pk.y = prev[m][2 * q4 + 1];
                    *(uint2*)(sm + OFF_TRM + (np * ST + fb) * 2) = pk;
                }
            }
            __syncthreads();   // writes visible before TW(s)
            TW(s);
        }
        __syncthreads();       // TW(4) reads done before epilogue writes

        const float bias = bsv[L][fo];
        if (L < 2) {
            #pragma unroll
            for (int m = 0; m < 2; m++) {
                unsigned short h[16];
                #pragma unroll
                for (int r = 0; r < 16; r++) {
                    h[r] = f2bf(fmaxf(acc[m][r] + bias, 0.f));
                    int n = (Mt0 + m) * 32 + (r & 3) + 8 * (r >> 2) + 4 * hh;
                    *(unsigned short*)(sm + OFF_TRM + (n * ST + fo) * 2) = h[r];
                }
                #pragma unroll
                for (int q4 = 0; q4 < 4; q4++) {
                    int nb = (Mt0 + m) * 32 + 8 * q4 + 4 * hh;
                    uint2 pk;
                    pk.x = (unsigned)h[4 * q4] | ((unsigned)h[4 * q4 + 1] << 16);
                    pk.y = (unsigned)h[4 * q4 + 2] | ((unsigned)h[4 * q4 + 3] << 16);
                    *(uint2*)(sm + OFF_TT + (fo * SAT + nb) * 2) = pk;
                }
            }
            __syncthreads();
        } else {
            float ssum = 0.f;
            #pragma unroll
            for (int m = 0; m < 2; m++) {
                #pragma unroll
                for (int r = 0; r < 16; r++) {
                    int n = (Mt0 + m) * 32 + (r & 3) + 8 * (r >> 2) + 4 * hh;
                    float h = fmaxf(acc[m][r] + bias, 0.f);
                    if (n < NPG) ssum += h;
                }
            }
            ssum += __shfl_xor(ssum, 32, 64);
            if (hh == 0) atomicAdd(&pool[fo], ssum);
            __syncthreads();
        }
    }

    // ---------------- BN + MLP + log_softmax ----------------
    if (tid < HF) {
        float gv = pool[tid] * (1.0f / NPG);
        gv = (gv - bnm[tid]) * rsqrtf(bnv[tid] + 1e-5f) * bng[tid] + bnb[tid];
        gvn[tid] = gv;
    }
    __syncthreads();
    if (tid < 32) {
        float a = fc1b[tid];
        for (int f = 0; f < HF; f++) a += gvn[f] * fc1w[f * 32 + tid];
        zf[tid] = fmaxf(a, 0.f);
    }
    __syncthreads();
    if (tid < 10) {
        float a = fc2b[tid];
        for (int k = 0; k < 32; k++) a += zf[k] * fc2w[k * 10 + tid];
        logits[tid] = a;
    }
    __syncthreads();
    if (tid == 0) {
        float m = logits[0];
        for (int i = 1; i < 10; i++) m = fmaxf(m, logits[i]);
        float s = 0.f;
        for (int i = 0; i < 10; i++) s += expf(logits[i] - m);
        lsep[0] = m + logf(s);
    }
    __syncthreads();
    if (tid < 10) out[g * 10 + tid] = logits[tid] - lsep[0];
}

extern "C" void kernel_launch(void* const* d_in, const int* in_sizes, int n_in,
                              void* d_out, int out_size, void* d_ws, size_t ws_size,
                              hipStream_t stream) {
    const float* x    = (const float*)d_in[0];
    const int*   ei   = (const int*)d_in[1];
    const float* lmax = (const float*)d_in[3];
    const float* W1   = (const float*)d_in[4];
    const float* b1   = (const float*)d_in[5];
    const float* W2   = (const float*)d_in[6];
    const float* b2   = (const float*)d_in[7];
    const float* W3   = (const float*)d_in[8];
    const float* b3   = (const float*)d_in[9];
    const float* bng  = (const float*)d_in[10];
    const float* bnb  = (const float*)d_in[11];
    const float* bnm  = (const float*)d_in[12];
    const float* bnv  = (const float*)d_in[13];
    const float* fc1w = (const float*)d_in[14];
    const float* fc1b = (const float*)d_in[15];
    const float* fc2w = (const float*)d_in[16];
    const float* fc2b = (const float*)d_in[17];

    const int E = in_sizes[1] / 2;
    const int G = in_sizes[3];
    const int epg = E / G;

    unsigned short* Wt = (unsigned short*)d_ws;

    wconv<<<(WT_TOTAL + 255) / 256, 256, 0, stream>>>(W1, W2, W3, Wt);

    hipFuncSetAttribute((const void*)cheb32t,
                        hipFuncAttributeMaxDynamicSharedMemorySize, SMEM_BYTES);

    cheb32t<<<G, 256, SMEM_BYTES, stream>>>(x, ei, lmax, Wt, b1, b2, b3,
                                            bng, bnb, bnm, bnv, fc1w, fc1b, fc2w, fc2b,
                                            (float*)d_out, E, epg);
}